// Round 6
// baseline (925.659 us; speedup 1.0000x reference)
//
#include <hip/hip_runtime.h>
#include <hip/hip_bf16.h>
#include <math.h>

#define N_NODES 100000
#define N_EDGES 800000

typedef float f32x4 __attribute__((ext_vector_type(4)));
typedef short bf16x8 __attribute__((ext_vector_type(8)));

__device__ inline unsigned short bf16_of(float f) {
    union { __hip_bfloat16 b; unsigned short u; } cv;
    cv.b = __float2bfloat16(f);
    return cv.u;
}
__device__ inline float f32_of(unsigned short u) {
    union { __hip_bfloat16 b; unsigned short u; } cv;
    cv.u = u;
    return __bfloat162float(cv.b);
}

// ================= degree / CSR build =================
__global__ void k_zero_deg(int* __restrict__ deg) {
    int i = blockIdx.x * blockDim.x + threadIdx.x;
    if (i < N_NODES) deg[i] = 0;
}

__global__ void k_hist(const int* __restrict__ edst, int* __restrict__ deg) {
    int e = blockIdx.x * blockDim.x + threadIdx.x;
    if (e < N_EDGES) atomicAdd(&deg[edst[e]], 1);
}

__global__ void k_dinv(const int* __restrict__ deg, float* __restrict__ dinv) {
    int i = blockIdx.x * blockDim.x + threadIdx.x;
    if (i < N_NODES) dinv[i] = rsqrtf((float)(deg[i] + 1));   // +1 self-loop
}

// exclusive scan, 256/block
__global__ void k_scan1(const int* __restrict__ deg, int* __restrict__ off,
                        int* __restrict__ bsum, int n) {
    __shared__ int s[256];
    int t = threadIdx.x;
    int i = blockIdx.x * 256 + t;
    int v = (i < n) ? deg[i] : 0;
    s[t] = v;
    __syncthreads();
    #pragma unroll
    for (int d = 1; d < 256; d <<= 1) {
        int x = (t >= d) ? s[t - d] : 0;
        __syncthreads();
        s[t] += x;
        __syncthreads();
    }
    if (i < n) off[i] = s[t] - v;            // exclusive within block
    if (t == 255) bsum[blockIdx.x] = s[255];
}

__global__ void k_scan2(int* __restrict__ bsum, int nb) {
    __shared__ int s[512];
    int t = threadIdx.x;
    int v = (t < nb) ? bsum[t] : 0;
    s[t] = v;
    __syncthreads();
    #pragma unroll
    for (int d = 1; d < 512; d <<= 1) {
        int x = (t >= d) ? s[t - d] : 0;
        __syncthreads();
        s[t] += x;
        __syncthreads();
    }
    if (t < nb) bsum[t] = s[t] - v;          // exclusive block offsets
}

__global__ void k_scan3(int* __restrict__ off, const int* __restrict__ bsum,
                        int* __restrict__ cur, int n) {
    int i = blockIdx.x * blockDim.x + threadIdx.x;
    if (i < n) {
        int o = off[i] + bsum[i >> 8];
        off[i] = o;
        cur[i] = o;
    }
    if (i == n) off[n] = N_EDGES;
}

__global__ void k_scatter(const int* __restrict__ esrc, const int* __restrict__ edst,
                          const float* __restrict__ dinv,
                          int* __restrict__ cur, int* __restrict__ csr_src,
                          float* __restrict__ csr_w) {
    int e = blockIdx.x * blockDim.x + threadIdx.x;
    if (e >= N_EDGES) return;
    int s = esrc[e], d = edst[e];
    int pos = atomicAdd(&cur[d], 1);
    csr_src[pos] = s;
    csr_w[pos] = dinv[s] * dinv[d];
}

// ================= bf16 hi/lo split of a 128x128 W into MFMA fragment layout ========
// frag index for (k, c): lane = ((k>>3)&3)*16 + (c&15), elem = k&7, tile = (k>>5)*8 + (c>>4)
__global__ void k_split_w(const float* __restrict__ W, unsigned short* __restrict__ Wh,
                          unsigned short* __restrict__ Wl) {
    int idx = blockIdx.x * 256 + threadIdx.x;
    if (idx >= 128 * 128) return;
    int k = idx >> 7, c = idx & 127;
    float wv = W[idx];
    unsigned short h = bf16_of(wv);
    unsigned short lo = bf16_of(wv - f32_of(h));
    int fi = (((k >> 5) * 8 + (c >> 4)) * 64 + (((k >> 3) & 3) * 16 + (c & 15))) * 8 + (k & 7);
    Wh[fi] = h;
    Wl[fi] = lo;
}

// ================= MFMA node GEMM: out = (relu?)in[N,128] @ W[128,128] =================
// bf16x3 error-compensated. 512 threads = 8 waves x 16 rows; R row-tiles per block.
// In-place safe (out==in): each wave reads only its own 16 rows (regs) before writing them.
template<bool RELU>
__global__ __launch_bounds__(512) void k_gemm_mfma(
    const float* __restrict__ in,
    const unsigned short* __restrict__ Whf, const unsigned short* __restrict__ Wlf,
    float* __restrict__ outp, int nrows, int rtiles)
{
    __shared__ __align__(16) unsigned short sWh[16384];
    __shared__ __align__(16) unsigned short sWl[16384];
    const int t = threadIdx.x;

    #pragma unroll
    for (int i = 0; i < 4; ++i) {
        ((float4*)sWh)[t + 512 * i] = ((const float4*)Whf)[t + 512 * i];
        ((float4*)sWl)[t + 512 * i] = ((const float4*)Wlf)[t + 512 * i];
    }
    __syncthreads();

    const int w = t >> 6, l = t & 63;
    const int lr = l & 15, lk = l >> 4;

    for (int r = 0; r < rtiles; ++r) {
        const int row0 = (blockIdx.x * rtiles + r) * 128;
        int arow = row0 + w * 16 + lr;
        if (arow >= nrows) arow = nrows - 1;     // clamp (stores are guarded)
        const float* inrow = in + (size_t)arow * 128 + lk * 8;

        bf16x8 ah[4], al[4];
        #pragma unroll
        for (int ks = 0; ks < 4; ++ks) {
            float4 p0 = *(const float4*)(inrow + ks * 32);
            float4 p1 = *(const float4*)(inrow + ks * 32 + 4);
            float z[8] = {p0.x, p0.y, p0.z, p0.w, p1.x, p1.y, p1.z, p1.w};
            #pragma unroll
            for (int e = 0; e < 8; ++e) {
                float zv = RELU ? fmaxf(z[e], 0.f) : z[e];
                unsigned short hu = bf16_of(zv);
                ah[ks][e] = (short)hu;
                al[ks][e] = (short)bf16_of(zv - f32_of(hu));
            }
        }

        f32x4 acc[8];
        #pragma unroll
        for (int ct = 0; ct < 8; ++ct) { f32x4 zz = {0.f, 0.f, 0.f, 0.f}; acc[ct] = zz; }

        #pragma unroll
        for (int ct = 0; ct < 8; ++ct) {
            #pragma unroll
            for (int ks = 0; ks < 4; ++ks) {
                const bf16x8 bh = *(const bf16x8*)(sWh + ((ks * 8 + ct) * 64 + l) * 8);
                const bf16x8 bl = *(const bf16x8*)(sWl + ((ks * 8 + ct) * 64 + l) * 8);
                acc[ct] = __builtin_amdgcn_mfma_f32_16x16x32_bf16(ah[ks], bh, acc[ct], 0, 0, 0);
                acc[ct] = __builtin_amdgcn_mfma_f32_16x16x32_bf16(ah[ks], bl, acc[ct], 0, 0, 0);
                acc[ct] = __builtin_amdgcn_mfma_f32_16x16x32_bf16(al[ks], bh, acc[ct], 0, 0, 0);
            }
        }

        // D: row m = lk*4 + j (within wave tile), col = ct*16 + lr
        #pragma unroll
        for (int j = 0; j < 4; ++j) {
            int m = row0 + w * 16 + lk * 4 + j;
            if (m < nrows) {
                #pragma unroll
                for (int ct = 0; ct < 8; ++ct)
                    outp[(size_t)m * 128 + ct * 16 + lr] = acc[ct][j];
            }
        }
    }
}

// ================= MFMA P/Q GEMM: P = relu(in)@Wm1_top, Q = relu(in)@Wm1_bot ==========
// Two passes sharing one LDS region; in-place safe for Q==in (input re-read each pass).
__global__ __launch_bounds__(512) void k_gemm_pq_mfma(
    const float* __restrict__ in,
    const unsigned short* __restrict__ Wh0, const unsigned short* __restrict__ Wl0,
    const unsigned short* __restrict__ Wh1, const unsigned short* __restrict__ Wl1,
    float* __restrict__ P, float* __restrict__ Q, int nrows, int rtiles)
{
    __shared__ __align__(16) unsigned short sWh[16384];
    __shared__ __align__(16) unsigned short sWl[16384];
    const int t = threadIdx.x;
    const int w = t >> 6, l = t & 63;
    const int lr = l & 15, lk = l >> 4;

    #pragma unroll
    for (int half = 0; half < 2; ++half) {
        const unsigned short* Whf = half ? Wh1 : Wh0;
        const unsigned short* Wlf = half ? Wl1 : Wl0;
        float* outp = half ? Q : P;
        if (half) __syncthreads();     // all waves done reading previous sW
        #pragma unroll
        for (int i = 0; i < 4; ++i) {
            ((float4*)sWh)[t + 512 * i] = ((const float4*)Whf)[t + 512 * i];
            ((float4*)sWl)[t + 512 * i] = ((const float4*)Wlf)[t + 512 * i];
        }
        __syncthreads();

        for (int r = 0; r < rtiles; ++r) {
            const int row0 = (blockIdx.x * rtiles + r) * 128;
            int arow = row0 + w * 16 + lr;
            if (arow >= nrows) arow = nrows - 1;
            const float* inrow = in + (size_t)arow * 128 + lk * 8;

            bf16x8 ah[4], al[4];
            #pragma unroll
            for (int ks = 0; ks < 4; ++ks) {
                float4 p0 = *(const float4*)(inrow + ks * 32);
                float4 p1 = *(const float4*)(inrow + ks * 32 + 4);
                float z[8] = {p0.x, p0.y, p0.z, p0.w, p1.x, p1.y, p1.z, p1.w};
                #pragma unroll
                for (int e = 0; e < 8; ++e) {
                    float zv = fmaxf(z[e], 0.f);
                    unsigned short hu = bf16_of(zv);
                    ah[ks][e] = (short)hu;
                    al[ks][e] = (short)bf16_of(zv - f32_of(hu));
                }
            }

            f32x4 acc[8];
            #pragma unroll
            for (int ct = 0; ct < 8; ++ct) { f32x4 zz = {0.f, 0.f, 0.f, 0.f}; acc[ct] = zz; }

            #pragma unroll
            for (int ct = 0; ct < 8; ++ct) {
                #pragma unroll
                for (int ks = 0; ks < 4; ++ks) {
                    const bf16x8 bh = *(const bf16x8*)(sWh + ((ks * 8 + ct) * 64 + l) * 8);
                    const bf16x8 bl = *(const bf16x8*)(sWl + ((ks * 8 + ct) * 64 + l) * 8);
                    acc[ct] = __builtin_amdgcn_mfma_f32_16x16x32_bf16(ah[ks], bh, acc[ct], 0, 0, 0);
                    acc[ct] = __builtin_amdgcn_mfma_f32_16x16x32_bf16(ah[ks], bl, acc[ct], 0, 0, 0);
                    acc[ct] = __builtin_amdgcn_mfma_f32_16x16x32_bf16(al[ks], bh, acc[ct], 0, 0, 0);
                }
            }

            #pragma unroll
            for (int j = 0; j < 4; ++j) {
                int m = row0 + w * 16 + lk * 4 + j;
                if (m < nrows) {
                    #pragma unroll
                    for (int ct = 0; ct < 8; ++ct)
                        outp[(size_t)m * 128 + ct * 16 + lr] = acc[ct][j];
                }
            }
        }
    }
}

// ================= CSR aggregation =================
// out[i][:] = bias[:] + dinv[i]^2 * raw[i][:] + sum_{e: dst=i} w_e * raw[src_e][:]
__global__ __launch_bounds__(256) void k_agg_csr(
    const float* __restrict__ raw, const float* __restrict__ dinv,
    const int* __restrict__ off, const int* __restrict__ csr_src,
    const float* __restrict__ csr_w, const float* __restrict__ bias,
    float* __restrict__ outp)
{
    const int t = threadIdx.x;
    const int node = blockIdx.x * 8 + (t >> 5);
    const int lane = t & 31;
    if (node >= N_NODES) return;

    float di = dinv[node];
    float w0 = di * di;
    float4 acc = ((const float4*)bias)[lane];
    float4 v = ((const float4*)raw)[(size_t)node * 32 + lane];
    acc.x += w0 * v.x; acc.y += w0 * v.y; acc.z += w0 * v.z; acc.w += w0 * v.w;

    int beg = off[node], end = off[node + 1];
    for (int j = beg; j < end; ++j) {
        int s = csr_src[j];
        float w = csr_w[j];
        float4 u = ((const float4*)raw)[(size_t)s * 32 + lane];
        acc.x += w * u.x; acc.y += w * u.y; acc.z += w * u.z; acc.w += w * u.w;
    }
    ((float4*)outp)[(size_t)node * 32 + lane] = acc;
}

// ================= fused edge MLP (MFMA bf16x3, 8 waves, 5 tiles/block) =================
// z1 = relu(P[src] + Q[dst] + bm1) in registers; z2 = relu(z1@Wm2+bm2) via MFMA;
// out = sigmoid(z2@Wm3+bm3)
#define EDGE_G 5
__global__ __launch_bounds__(512) void k_edge_mlp_mfma(
    const int* __restrict__ esrc, const int* __restrict__ edst,
    const float* __restrict__ P, const float* __restrict__ Q,
    const float* __restrict__ bm1,
    const unsigned short* __restrict__ Whf, const unsigned short* __restrict__ Wlf,
    const float* __restrict__ bm2,
    const float* __restrict__ Wm3, const float* __restrict__ bm3,
    float* __restrict__ outp)
{
    __shared__ __align__(16) unsigned short sWh[16384];
    __shared__ __align__(16) unsigned short sWl[16384];
    const int t = threadIdx.x;

    #pragma unroll
    for (int i = 0; i < 4; ++i) {
        ((float4*)sWh)[t + 512 * i] = ((const float4*)Whf)[t + 512 * i];
        ((float4*)sWl)[t + 512 * i] = ((const float4*)Wlf)[t + 512 * i];
    }
    __syncthreads();

    const int w = t >> 6, l = t & 63;
    const int lr = l & 15, lk = l >> 4;

    // per-lane loop-invariant scalars
    float bv2[8], w3v[8];
    #pragma unroll
    for (int ct = 0; ct < 8; ++ct) {
        bv2[ct] = bm2[ct * 16 + lr];
        w3v[ct] = Wm3[ct * 16 + lr];
    }
    const float b3 = bm3[0];
    const float* brow = bm1 + lk * 8;

    for (int g = 0; g < EDGE_G; ++g) {
        const int e0 = (blockIdx.x * EDGE_G + g) * 128;
        const int erow = e0 + w * 16 + lr;
        const int s = esrc[erow], d = edst[erow];
        const float* prow = P + (size_t)s * 128 + lk * 8;
        const float* qrow = Q + (size_t)d * 128 + lk * 8;

        bf16x8 ah[4], al[4];
        #pragma unroll
        for (int ks = 0; ks < 4; ++ks) {
            float4 p0 = *(const float4*)(prow + ks * 32);
            float4 p1 = *(const float4*)(prow + ks * 32 + 4);
            float4 q0 = *(const float4*)(qrow + ks * 32);
            float4 q1 = *(const float4*)(qrow + ks * 32 + 4);
            float4 b0 = *(const float4*)(brow + ks * 32);
            float4 b1 = *(const float4*)(brow + ks * 32 + 4);
            float z[8];
            z[0] = fmaxf(p0.x + q0.x + b0.x, 0.f);
            z[1] = fmaxf(p0.y + q0.y + b0.y, 0.f);
            z[2] = fmaxf(p0.z + q0.z + b0.z, 0.f);
            z[3] = fmaxf(p0.w + q0.w + b0.w, 0.f);
            z[4] = fmaxf(p1.x + q1.x + b1.x, 0.f);
            z[5] = fmaxf(p1.y + q1.y + b1.y, 0.f);
            z[6] = fmaxf(p1.z + q1.z + b1.z, 0.f);
            z[7] = fmaxf(p1.w + q1.w + b1.w, 0.f);
            #pragma unroll
            for (int e = 0; e < 8; ++e) {
                unsigned short hu = bf16_of(z[e]);
                ah[ks][e] = (short)hu;
                al[ks][e] = (short)bf16_of(z[e] - f32_of(hu));
            }
        }

        f32x4 acc[8];
        #pragma unroll
        for (int ct = 0; ct < 8; ++ct) {
            f32x4 a = {bv2[ct], bv2[ct], bv2[ct], bv2[ct]};
            acc[ct] = a;
        }

        #pragma unroll
        for (int ct = 0; ct < 8; ++ct) {
            #pragma unroll
            for (int ks = 0; ks < 4; ++ks) {
                const bf16x8 bh = *(const bf16x8*)(sWh + ((ks * 8 + ct) * 64 + l) * 8);
                const bf16x8 bl = *(const bf16x8*)(sWl + ((ks * 8 + ct) * 64 + l) * 8);
                acc[ct] = __builtin_amdgcn_mfma_f32_16x16x32_bf16(ah[ks], bh, acc[ct], 0, 0, 0);
                acc[ct] = __builtin_amdgcn_mfma_f32_16x16x32_bf16(ah[ks], bl, acc[ct], 0, 0, 0);
                acc[ct] = __builtin_amdgcn_mfma_f32_16x16x32_bf16(al[ks], bh, acc[ct], 0, 0, 0);
            }
        }

        #pragma unroll
        for (int j = 0; j < 4; ++j) {
            float pj = 0.f;
            #pragma unroll
            for (int ct = 0; ct < 8; ++ct) pj += fmaxf(acc[ct][j], 0.f) * w3v[ct];
            pj += __shfl_xor(pj, 1);
            pj += __shfl_xor(pj, 2);
            pj += __shfl_xor(pj, 4);
            pj += __shfl_xor(pj, 8);
            if (lr == 0)
                outp[e0 + w * 16 + lk * 4 + j] = 1.f / (1.f + expf(-(pj + b3)));
        }
    }
}

// ================= launch =================
extern "C" void kernel_launch(void* const* d_in, const int* in_sizes, int n_in,
                              void* d_out, int out_size, void* d_ws, size_t ws_size,
                              hipStream_t stream) {
    const float* x   = (const float*)d_in[0];
    const int*   ei  = (const int*)d_in[1];
    const float* W1  = (const float*)d_in[2];
    const float* b1  = (const float*)d_in[3];
    const float* W2  = (const float*)d_in[4];
    const float* b2  = (const float*)d_in[5];
    const float* Wm1 = (const float*)d_in[6];
    const float* bm1 = (const float*)d_in[7];
    const float* Wm2 = (const float*)d_in[8];
    const float* bm2 = (const float*)d_in[9];
    const float* Wm3 = (const float*)d_in[10];
    const float* bm3 = (const float*)d_in[11];
    const int* esrc = ei;
    const int* edst = ei + N_EDGES;
    float* outp = (float*)d_out;

    // workspace layout
    float* ws = (float*)d_ws;
    float* dinv = ws;                                   // 100096 floats
    float* A = ws + 100096;                             // N*128
    float* B = A + (size_t)N_NODES * 128;               // N*128
    int* deg     = (int*)(B + (size_t)N_NODES * 128);   // N
    int* off     = deg + N_NODES;                       // N+1
    int* cur     = off + N_NODES + 1;                   // N
    int* bsum    = cur + N_NODES;                       // 512
    int* csr_src = bsum + 512;                          // E
    float* csr_w = (float*)(csr_src + N_EDGES);         // E
    unsigned short* frag = (unsigned short*)(csr_w + N_EDGES);
    unsigned short* W1h   = frag;                 unsigned short* W1l   = frag + 16384;
    unsigned short* W2h   = frag + 2 * 16384;     unsigned short* W2l   = frag + 3 * 16384;
    unsigned short* Wm1ah = frag + 4 * 16384;     unsigned short* Wm1al = frag + 5 * 16384;
    unsigned short* Wm1bh = frag + 6 * 16384;     unsigned short* Wm1bl = frag + 7 * 16384;
    unsigned short* Wm2h  = frag + 8 * 16384;     unsigned short* Wm2l  = frag + 9 * 16384;

    const int nb = (N_NODES + 255) / 256;               // 391 scan blocks

    // ---- CSR build + W splits ----
    k_zero_deg<<<nb, 256, 0, stream>>>(deg);
    k_hist<<<(N_EDGES + 255) / 256, 256, 0, stream>>>(edst, deg);
    k_dinv<<<nb, 256, 0, stream>>>(deg, dinv);
    k_scan1<<<nb, 256, 0, stream>>>(deg, off, bsum, N_NODES);
    k_scan2<<<1, 512, 0, stream>>>(bsum, nb);
    k_scan3<<<(N_NODES + 256) / 256, 256, 0, stream>>>(off, bsum, cur, N_NODES);
    k_scatter<<<(N_EDGES + 255) / 256, 256, 0, stream>>>(esrc, edst, dinv, cur, csr_src, csr_w);
    k_split_w<<<64, 256, 0, stream>>>(W1, W1h, W1l);
    k_split_w<<<64, 256, 0, stream>>>(W2, W2h, W2l);
    k_split_w<<<64, 256, 0, stream>>>(Wm1, Wm1ah, Wm1al);
    k_split_w<<<64, 256, 0, stream>>>(Wm1 + 128 * 128, Wm1bh, Wm1bl);
    k_split_w<<<64, 256, 0, stream>>>(Wm2, Wm2h, Wm2l);

    const int RT = 4;                                   // row tiles per block (128 rows each)
    const int gemm_blocks = (N_NODES + 128 * RT - 1) / (128 * RT);   // 196
    const int agg_blocks = (N_NODES + 7) / 8;

    // ---- layer 1: A = x @ W1 ; B = b1 + norm-agg(A) ----
    k_gemm_mfma<false><<<gemm_blocks, 512, 0, stream>>>(x, W1h, W1l, A, N_NODES, RT);
    k_agg_csr<<<agg_blocks, 256, 0, stream>>>(A, dinv, off, csr_src, csr_w, b1, B);

    // ---- layer 2: A = relu(B) @ W2 ; B = b2 + norm-agg(A) ----
    k_gemm_mfma<true><<<gemm_blocks, 512, 0, stream>>>(B, W2h, W2l, A, N_NODES, RT);
    k_agg_csr<<<agg_blocks, 256, 0, stream>>>(A, dinv, off, csr_src, csr_w, b2, B);

    // ---- edge-MLP layer-1 decomposition: P -> A, Q -> B (in-place safe) ----
    k_gemm_pq_mfma<<<gemm_blocks, 512, 0, stream>>>(B, Wm1ah, Wm1al, Wm1bh, Wm1bl,
                                                    A, B, N_NODES, RT);

    // ---- fused edge MLP on MFMA: 1250 blocks x 5 tiles x 128 edges ----
    k_edge_mlp_mfma<<<N_EDGES / (128 * EDGE_G), 512, 0, stream>>>(
        esrc, edst, A, B, bm1, Wm2h, Wm2l, bm2, Wm3, bm3, outp);
}

// Round 7
// 592.124 us; speedup vs baseline: 1.5633x; 1.5633x over previous
//
#include <hip/hip_runtime.h>
#include <hip/hip_bf16.h>
#include <math.h>

#define N_NODES 100000
#define N_EDGES 800000

typedef float f32x4 __attribute__((ext_vector_type(4)));
typedef short bf16x8 __attribute__((ext_vector_type(8)));

__device__ inline unsigned short bf16_of(float f) {
    union { __hip_bfloat16 b; unsigned short u; } cv;
    cv.b = __float2bfloat16(f);
    return cv.u;
}
__device__ inline float f32_of(unsigned short u) {
    union { __hip_bfloat16 b; unsigned short u; } cv;
    cv.u = u;
    return __bfloat162float(cv.b);
}

// ================= degree / CSR build =================
__global__ void k_zero_deg(int* __restrict__ deg) {
    int i = blockIdx.x * blockDim.x + threadIdx.x;
    if (i < N_NODES) deg[i] = 0;
}

__global__ void k_hist(const int* __restrict__ edst, int* __restrict__ deg) {
    int e = blockIdx.x * blockDim.x + threadIdx.x;
    if (e < N_EDGES) atomicAdd(&deg[edst[e]], 1);
}

__global__ void k_dinv(const int* __restrict__ deg, float* __restrict__ dinv) {
    int i = blockIdx.x * blockDim.x + threadIdx.x;
    if (i < N_NODES) dinv[i] = rsqrtf((float)(deg[i] + 1));   // +1 self-loop
}

// exclusive scan, 256/block
__global__ void k_scan1(const int* __restrict__ deg, int* __restrict__ off,
                        int* __restrict__ bsum, int n) {
    __shared__ int s[256];
    int t = threadIdx.x;
    int i = blockIdx.x * 256 + t;
    int v = (i < n) ? deg[i] : 0;
    s[t] = v;
    __syncthreads();
    #pragma unroll
    for (int d = 1; d < 256; d <<= 1) {
        int x = (t >= d) ? s[t - d] : 0;
        __syncthreads();
        s[t] += x;
        __syncthreads();
    }
    if (i < n) off[i] = s[t] - v;            // exclusive within block
    if (t == 255) bsum[blockIdx.x] = s[255];
}

__global__ void k_scan2(int* __restrict__ bsum, int nb) {
    __shared__ int s[512];
    int t = threadIdx.x;
    int v = (t < nb) ? bsum[t] : 0;
    s[t] = v;
    __syncthreads();
    #pragma unroll
    for (int d = 1; d < 512; d <<= 1) {
        int x = (t >= d) ? s[t - d] : 0;
        __syncthreads();
        s[t] += x;
        __syncthreads();
    }
    if (t < nb) bsum[t] = s[t] - v;          // exclusive block offsets
}

__global__ void k_scan3(int* __restrict__ off, const int* __restrict__ bsum,
                        int* __restrict__ cur, int n) {
    int i = blockIdx.x * blockDim.x + threadIdx.x;
    if (i < n) {
        int o = off[i] + bsum[i >> 8];
        off[i] = o;
        cur[i] = o;
    }
    if (i == n) off[n] = N_EDGES;
}

__global__ void k_scatter(const int* __restrict__ esrc, const int* __restrict__ edst,
                          const float* __restrict__ dinv,
                          int* __restrict__ cur, int* __restrict__ csr_src,
                          float* __restrict__ csr_w) {
    int e = blockIdx.x * blockDim.x + threadIdx.x;
    if (e >= N_EDGES) return;
    int s = esrc[e], d = edst[e];
    int pos = atomicAdd(&cur[d], 1);
    csr_src[pos] = s;
    csr_w[pos] = dinv[s] * dinv[d];
}

// ================= bf16 hi/lo split of a 128x128 W into MFMA fragment layout ========
// frag index for (k, c): lane = ((k>>3)&3)*16 + (c&15), elem = k&7, tile = (k>>5)*8 + (c>>4)
__global__ void k_split_w(const float* __restrict__ W, unsigned short* __restrict__ Wh,
                          unsigned short* __restrict__ Wl) {
    int idx = blockIdx.x * 256 + threadIdx.x;
    if (idx >= 128 * 128) return;
    int k = idx >> 7, c = idx & 127;
    float wv = W[idx];
    unsigned short h = bf16_of(wv);
    unsigned short lo = bf16_of(wv - f32_of(h));
    int fi = (((k >> 5) * 8 + (c >> 4)) * 64 + (((k >> 3) & 3) * 16 + (c & 15))) * 8 + (k & 7);
    Wh[fi] = h;
    Wl[fi] = lo;
}

// ================= MFMA node GEMM: out = (relu?)in[N,128] @ W[128,128] =================
// bf16x3 error-compensated. 512 threads = 8 waves x 16 rows; R row-tiles per block.
// In-place safe (out==in): each wave reads only its own 16 rows (regs) before writing them.
template<bool RELU>
__global__ __launch_bounds__(512) void k_gemm_mfma(
    const float* __restrict__ in,
    const unsigned short* __restrict__ Whf, const unsigned short* __restrict__ Wlf,
    float* __restrict__ outp, int nrows, int rtiles)
{
    __shared__ __align__(16) unsigned short sWh[16384];
    __shared__ __align__(16) unsigned short sWl[16384];
    const int t = threadIdx.x;

    #pragma unroll
    for (int i = 0; i < 4; ++i) {
        ((float4*)sWh)[t + 512 * i] = ((const float4*)Whf)[t + 512 * i];
        ((float4*)sWl)[t + 512 * i] = ((const float4*)Wlf)[t + 512 * i];
    }
    __syncthreads();

    const int w = t >> 6, l = t & 63;
    const int lr = l & 15, lk = l >> 4;

    for (int r = 0; r < rtiles; ++r) {
        const int row0 = (blockIdx.x * rtiles + r) * 128;
        int arow = row0 + w * 16 + lr;
        if (arow >= nrows) arow = nrows - 1;     // clamp (stores are guarded)
        const float* inrow = in + (size_t)arow * 128 + lk * 8;

        bf16x8 ah[4], al[4];
        #pragma unroll
        for (int ks = 0; ks < 4; ++ks) {
            float4 p0 = *(const float4*)(inrow + ks * 32);
            float4 p1 = *(const float4*)(inrow + ks * 32 + 4);
            float z[8] = {p0.x, p0.y, p0.z, p0.w, p1.x, p1.y, p1.z, p1.w};
            #pragma unroll
            for (int e = 0; e < 8; ++e) {
                float zv = RELU ? fmaxf(z[e], 0.f) : z[e];
                unsigned short hu = bf16_of(zv);
                ah[ks][e] = (short)hu;
                al[ks][e] = (short)bf16_of(zv - f32_of(hu));
            }
        }

        f32x4 acc[8];
        #pragma unroll
        for (int ct = 0; ct < 8; ++ct) { f32x4 zz = {0.f, 0.f, 0.f, 0.f}; acc[ct] = zz; }

        #pragma unroll
        for (int ct = 0; ct < 8; ++ct) {
            #pragma unroll
            for (int ks = 0; ks < 4; ++ks) {
                const bf16x8 bh = *(const bf16x8*)(sWh + ((ks * 8 + ct) * 64 + l) * 8);
                const bf16x8 bl = *(const bf16x8*)(sWl + ((ks * 8 + ct) * 64 + l) * 8);
                acc[ct] = __builtin_amdgcn_mfma_f32_16x16x32_bf16(ah[ks], bh, acc[ct], 0, 0, 0);
                acc[ct] = __builtin_amdgcn_mfma_f32_16x16x32_bf16(ah[ks], bl, acc[ct], 0, 0, 0);
                acc[ct] = __builtin_amdgcn_mfma_f32_16x16x32_bf16(al[ks], bh, acc[ct], 0, 0, 0);
            }
        }

        // D: row m = lk*4 + j (within wave tile), col = ct*16 + lr
        #pragma unroll
        for (int j = 0; j < 4; ++j) {
            int m = row0 + w * 16 + lk * 4 + j;
            if (m < nrows) {
                #pragma unroll
                for (int ct = 0; ct < 8; ++ct)
                    outp[(size_t)m * 128 + ct * 16 + lr] = acc[ct][j];
            }
        }
    }
}

// ================= MFMA P/Q GEMM: P = relu(in)@Wm1_top, Q = relu(in)@Wm1_bot ==========
// Two passes sharing one LDS region; in-place safe for Q==in (input re-read each pass).
__global__ __launch_bounds__(512) void k_gemm_pq_mfma(
    const float* __restrict__ in,
    const unsigned short* __restrict__ Wh0, const unsigned short* __restrict__ Wl0,
    const unsigned short* __restrict__ Wh1, const unsigned short* __restrict__ Wl1,
    float* __restrict__ P, float* __restrict__ Q, int nrows, int rtiles)
{
    __shared__ __align__(16) unsigned short sWh[16384];
    __shared__ __align__(16) unsigned short sWl[16384];
    const int t = threadIdx.x;
    const int w = t >> 6, l = t & 63;
    const int lr = l & 15, lk = l >> 4;

    #pragma unroll
    for (int half = 0; half < 2; ++half) {
        const unsigned short* Whf = half ? Wh1 : Wh0;
        const unsigned short* Wlf = half ? Wl1 : Wl0;
        float* outp = half ? Q : P;
        if (half) __syncthreads();     // all waves done reading previous sW
        #pragma unroll
        for (int i = 0; i < 4; ++i) {
            ((float4*)sWh)[t + 512 * i] = ((const float4*)Whf)[t + 512 * i];
            ((float4*)sWl)[t + 512 * i] = ((const float4*)Wlf)[t + 512 * i];
        }
        __syncthreads();

        for (int r = 0; r < rtiles; ++r) {
            const int row0 = (blockIdx.x * rtiles + r) * 128;
            int arow = row0 + w * 16 + lr;
            if (arow >= nrows) arow = nrows - 1;
            const float* inrow = in + (size_t)arow * 128 + lk * 8;

            bf16x8 ah[4], al[4];
            #pragma unroll
            for (int ks = 0; ks < 4; ++ks) {
                float4 p0 = *(const float4*)(inrow + ks * 32);
                float4 p1 = *(const float4*)(inrow + ks * 32 + 4);
                float z[8] = {p0.x, p0.y, p0.z, p0.w, p1.x, p1.y, p1.z, p1.w};
                #pragma unroll
                for (int e = 0; e < 8; ++e) {
                    float zv = fmaxf(z[e], 0.f);
                    unsigned short hu = bf16_of(zv);
                    ah[ks][e] = (short)hu;
                    al[ks][e] = (short)bf16_of(zv - f32_of(hu));
                }
            }

            f32x4 acc[8];
            #pragma unroll
            for (int ct = 0; ct < 8; ++ct) { f32x4 zz = {0.f, 0.f, 0.f, 0.f}; acc[ct] = zz; }

            #pragma unroll
            for (int ct = 0; ct < 8; ++ct) {
                #pragma unroll
                for (int ks = 0; ks < 4; ++ks) {
                    const bf16x8 bh = *(const bf16x8*)(sWh + ((ks * 8 + ct) * 64 + l) * 8);
                    const bf16x8 bl = *(const bf16x8*)(sWl + ((ks * 8 + ct) * 64 + l) * 8);
                    acc[ct] = __builtin_amdgcn_mfma_f32_16x16x32_bf16(ah[ks], bh, acc[ct], 0, 0, 0);
                    acc[ct] = __builtin_amdgcn_mfma_f32_16x16x32_bf16(ah[ks], bl, acc[ct], 0, 0, 0);
                    acc[ct] = __builtin_amdgcn_mfma_f32_16x16x32_bf16(al[ks], bh, acc[ct], 0, 0, 0);
                }
            }

            #pragma unroll
            for (int j = 0; j < 4; ++j) {
                int m = row0 + w * 16 + lk * 4 + j;
                if (m < nrows) {
                    #pragma unroll
                    for (int ct = 0; ct < 8; ++ct)
                        outp[(size_t)m * 128 + ct * 16 + lr] = acc[ct][j];
                }
            }
        }
    }
}

// ================= CSR aggregation =================
// out[i][:] = bias[:] + dinv[i]^2 * raw[i][:] + sum_{e: dst=i} w_e * raw[src_e][:]
__global__ __launch_bounds__(256) void k_agg_csr(
    const float* __restrict__ raw, const float* __restrict__ dinv,
    const int* __restrict__ off, const int* __restrict__ csr_src,
    const float* __restrict__ csr_w, const float* __restrict__ bias,
    float* __restrict__ outp)
{
    const int t = threadIdx.x;
    const int node = blockIdx.x * 8 + (t >> 5);
    const int lane = t & 31;
    if (node >= N_NODES) return;

    float di = dinv[node];
    float w0 = di * di;
    float4 acc = ((const float4*)bias)[lane];
    float4 v = ((const float4*)raw)[(size_t)node * 32 + lane];
    acc.x += w0 * v.x; acc.y += w0 * v.y; acc.z += w0 * v.z; acc.w += w0 * v.w;

    int beg = off[node], end = off[node + 1];
    for (int j = beg; j < end; ++j) {
        int s = csr_src[j];
        float w = csr_w[j];
        float4 u = ((const float4*)raw)[(size_t)s * 32 + lane];
        acc.x += w * u.x; acc.y += w * u.y; acc.z += w * u.z; acc.w += w * u.w;
    }
    ((float4*)outp)[(size_t)node * 32 + lane] = acc;
}

// ================= fused edge MLP (MFMA bf16x3) — round-5 proven shape =================
// z1 = relu(P[src] + Q[dst] + bm1) built in registers as A-frags;
// z2 = relu(z1 @ Wm2 + bm2) via 16x16x32 bf16 MFMA hi/lo split; out = sigmoid(z2@Wm3+bm3)
__global__ __launch_bounds__(256) void k_edge_mlp_mfma(
    const int* __restrict__ esrc, const int* __restrict__ edst,
    const float* __restrict__ P, const float* __restrict__ Q,
    const float* __restrict__ bm1,
    const unsigned short* __restrict__ Whf, const unsigned short* __restrict__ Wlf,
    const float* __restrict__ bm2,
    const float* __restrict__ Wm3, const float* __restrict__ bm3,
    float* __restrict__ outp)
{
    __shared__ __align__(16) unsigned short sWh[16384];   // 32 KB, fragment layout
    __shared__ __align__(16) unsigned short sWl[16384];   // 32 KB
    __shared__ int sIdx[2][64];

    const int t = threadIdx.x;
    const int e0 = blockIdx.x * 64;

    // linear stage of pre-swizzled W fragments (2048 float4 each)
    #pragma unroll
    for (int i = 0; i < 8; ++i) {
        ((float4*)sWh)[t + 256 * i] = ((const float4*)Whf)[t + 256 * i];
        ((float4*)sWl)[t + 256 * i] = ((const float4*)Wlf)[t + 256 * i];
    }
    if (t < 64) sIdx[0][t] = esrc[e0 + t];
    else if (t < 128) sIdx[1][t - 64] = edst[e0 + t - 64];
    __syncthreads();

    const int w = t >> 6;          // wave id: rows w*16 .. w*16+15
    const int l = t & 63;
    const int lr = l & 15;         // A row within tile / D col
    const int lk = l >> 4;         // k-block
    const int row = w * 16 + lr;
    const int s = sIdx[0][row], d = sIdx[1][row];
    const float* prow = P + (size_t)s * 128 + lk * 8;
    const float* qrow = Q + (size_t)d * 128 + lk * 8;
    const float* brow = bm1 + lk * 8;

    // build A-fragments (z1 hi/lo) in registers
    bf16x8 ah[4], al[4];
    #pragma unroll
    for (int ks = 0; ks < 4; ++ks) {
        float4 p0 = *(const float4*)(prow + ks * 32);
        float4 p1 = *(const float4*)(prow + ks * 32 + 4);
        float4 q0 = *(const float4*)(qrow + ks * 32);
        float4 q1 = *(const float4*)(qrow + ks * 32 + 4);
        float4 b0 = *(const float4*)(brow + ks * 32);
        float4 b1 = *(const float4*)(brow + ks * 32 + 4);
        float z[8];
        z[0] = fmaxf(p0.x + q0.x + b0.x, 0.f);
        z[1] = fmaxf(p0.y + q0.y + b0.y, 0.f);
        z[2] = fmaxf(p0.z + q0.z + b0.z, 0.f);
        z[3] = fmaxf(p0.w + q0.w + b0.w, 0.f);
        z[4] = fmaxf(p1.x + q1.x + b1.x, 0.f);
        z[5] = fmaxf(p1.y + q1.y + b1.y, 0.f);
        z[6] = fmaxf(p1.z + q1.z + b1.z, 0.f);
        z[7] = fmaxf(p1.w + q1.w + b1.w, 0.f);
        #pragma unroll
        for (int e = 0; e < 8; ++e) {
            unsigned short hu = bf16_of(z[e]);
            ah[ks][e] = (short)hu;
            al[ks][e] = (short)bf16_of(z[e] - f32_of(hu));
        }
    }

    // C = z1 @ Wm2 + bm2  (8 col tiles of 16)
    f32x4 acc[8];
    #pragma unroll
    for (int ct = 0; ct < 8; ++ct) {
        float bv = bm2[ct * 16 + lr];
        f32x4 a = {bv, bv, bv, bv};
        acc[ct] = a;
    }

    #pragma unroll
    for (int ct = 0; ct < 8; ++ct) {
        #pragma unroll
        for (int ks = 0; ks < 4; ++ks) {
            const bf16x8 bh = *(const bf16x8*)(sWh + ((ks * 8 + ct) * 64 + l) * 8);
            const bf16x8 bl = *(const bf16x8*)(sWl + ((ks * 8 + ct) * 64 + l) * 8);
            acc[ct] = __builtin_amdgcn_mfma_f32_16x16x32_bf16(ah[ks], bh, acc[ct], 0, 0, 0);
            acc[ct] = __builtin_amdgcn_mfma_f32_16x16x32_bf16(ah[ks], bl, acc[ct], 0, 0, 0);
            acc[ct] = __builtin_amdgcn_mfma_f32_16x16x32_bf16(al[ks], bh, acc[ct], 0, 0, 0);
        }
    }

    // out = sigmoid(relu(C) @ Wm3 + bm3); D layout: col = lr, row = lk*4 + reg
    float w3v[8];
    #pragma unroll
    for (int ct = 0; ct < 8; ++ct) w3v[ct] = Wm3[ct * 16 + lr];
    float b3 = bm3[0];
    #pragma unroll
    for (int j = 0; j < 4; ++j) {
        float pj = 0.f;
        #pragma unroll
        for (int ct = 0; ct < 8; ++ct) pj += fmaxf(acc[ct][j], 0.f) * w3v[ct];
        pj += __shfl_xor(pj, 1);
        pj += __shfl_xor(pj, 2);
        pj += __shfl_xor(pj, 4);
        pj += __shfl_xor(pj, 8);
        if (lr == 0)
            outp[e0 + w * 16 + lk * 4 + j] = 1.f / (1.f + expf(-(pj + b3)));
    }
}

// ================= launch =================
extern "C" void kernel_launch(void* const* d_in, const int* in_sizes, int n_in,
                              void* d_out, int out_size, void* d_ws, size_t ws_size,
                              hipStream_t stream) {
    const float* x   = (const float*)d_in[0];
    const int*   ei  = (const int*)d_in[1];
    const float* W1  = (const float*)d_in[2];
    const float* b1  = (const float*)d_in[3];
    const float* W2  = (const float*)d_in[4];
    const float* b2  = (const float*)d_in[5];
    const float* Wm1 = (const float*)d_in[6];
    const float* bm1 = (const float*)d_in[7];
    const float* Wm2 = (const float*)d_in[8];
    const float* bm2 = (const float*)d_in[9];
    const float* Wm3 = (const float*)d_in[10];
    const float* bm3 = (const float*)d_in[11];
    const int* esrc = ei;
    const int* edst = ei + N_EDGES;
    float* outp = (float*)d_out;

    // workspace layout
    float* ws = (float*)d_ws;
    float* dinv = ws;                                   // 100096 floats
    float* A = ws + 100096;                             // N*128
    float* B = A + (size_t)N_NODES * 128;               // N*128
    int* deg     = (int*)(B + (size_t)N_NODES * 128);   // N
    int* off     = deg + N_NODES;                       // N+1
    int* cur     = off + N_NODES + 1;                   // N
    int* bsum    = cur + N_NODES;                       // 512
    int* csr_src = bsum + 512;                          // E
    float* csr_w = (float*)(csr_src + N_EDGES);         // E
    unsigned short* frag = (unsigned short*)(csr_w + N_EDGES);
    unsigned short* W1h   = frag;                 unsigned short* W1l   = frag + 16384;
    unsigned short* W2h   = frag + 2 * 16384;     unsigned short* W2l   = frag + 3 * 16384;
    unsigned short* Wm1ah = frag + 4 * 16384;     unsigned short* Wm1al = frag + 5 * 16384;
    unsigned short* Wm1bh = frag + 6 * 16384;     unsigned short* Wm1bl = frag + 7 * 16384;
    unsigned short* Wm2h  = frag + 8 * 16384;     unsigned short* Wm2l  = frag + 9 * 16384;

    const int nb = (N_NODES + 255) / 256;               // 391 scan blocks

    // ---- CSR build + W splits ----
    k_zero_deg<<<nb, 256, 0, stream>>>(deg);
    k_hist<<<(N_EDGES + 255) / 256, 256, 0, stream>>>(edst, deg);
    k_dinv<<<nb, 256, 0, stream>>>(deg, dinv);
    k_scan1<<<nb, 256, 0, stream>>>(deg, off, bsum, N_NODES);
    k_scan2<<<1, 512, 0, stream>>>(bsum, nb);
    k_scan3<<<(N_NODES + 256) / 256, 256, 0, stream>>>(off, bsum, cur, N_NODES);
    k_scatter<<<(N_EDGES + 255) / 256, 256, 0, stream>>>(esrc, edst, dinv, cur, csr_src, csr_w);
    k_split_w<<<64, 256, 0, stream>>>(W1, W1h, W1l);
    k_split_w<<<64, 256, 0, stream>>>(W2, W2h, W2l);
    k_split_w<<<64, 256, 0, stream>>>(Wm1, Wm1ah, Wm1al);
    k_split_w<<<64, 256, 0, stream>>>(Wm1 + 128 * 128, Wm1bh, Wm1bl);
    k_split_w<<<64, 256, 0, stream>>>(Wm2, Wm2h, Wm2l);

    const int RT = 4;                                   // row tiles per block (128 rows each)
    const int gemm_blocks = (N_NODES + 128 * RT - 1) / (128 * RT);   // 196
    const int agg_blocks = (N_NODES + 7) / 8;

    // ---- layer 1: A = x @ W1 ; B = b1 + norm-agg(A) ----
    k_gemm_mfma<false><<<gemm_blocks, 512, 0, stream>>>(x, W1h, W1l, A, N_NODES, RT);
    k_agg_csr<<<agg_blocks, 256, 0, stream>>>(A, dinv, off, csr_src, csr_w, b1, B);

    // ---- layer 2: A = relu(B) @ W2 ; B = b2 + norm-agg(A) ----
    k_gemm_mfma<true><<<gemm_blocks, 512, 0, stream>>>(B, W2h, W2l, A, N_NODES, RT);
    k_agg_csr<<<agg_blocks, 256, 0, stream>>>(A, dinv, off, csr_src, csr_w, b2, B);

    // ---- edge-MLP layer-1 decomposition: P -> A, Q -> B (in-place safe) ----
    k_gemm_pq_mfma<<<gemm_blocks, 512, 0, stream>>>(B, Wm1ah, Wm1al, Wm1bh, Wm1bl,
                                                    A, B, N_NODES, RT);

    // ---- fused edge MLP on MFMA: round-5 proven shape (64 edges / 256 threads) ----
    k_edge_mlp_mfma<<<N_EDGES / 64, 256, 0, stream>>>(esrc, edst, A, B, bm1,
                                                      Wm2h, Wm2l, bm2, Wm3, bm3, outp);
}

// Round 8
// 533.784 us; speedup vs baseline: 1.7341x; 1.1093x over previous
//
#include <hip/hip_runtime.h>
#include <hip/hip_bf16.h>
#include <math.h>

#define N_NODES 100000
#define N_EDGES 800000

typedef float f32x4 __attribute__((ext_vector_type(4)));
typedef short bf16x8 __attribute__((ext_vector_type(8)));

__device__ inline unsigned short bf16_of(float f) {
    union { __hip_bfloat16 b; unsigned short u; } cv;
    cv.b = __float2bfloat16(f);
    return cv.u;
}
__device__ inline float f32_of(unsigned short u) {
    union { __hip_bfloat16 b; unsigned short u; } cv;
    cv.u = u;
    return __bfloat162float(cv.b);
}

// ================= degree / CSR build =================
__global__ void k_zero_deg(int* __restrict__ deg) {
    int i = blockIdx.x * blockDim.x + threadIdx.x;
    if (i < N_NODES) deg[i] = 0;
}

__global__ void k_hist(const int* __restrict__ edst, int* __restrict__ deg) {
    int e = blockIdx.x * blockDim.x + threadIdx.x;
    if (e < N_EDGES) atomicAdd(&deg[edst[e]], 1);
}

// exclusive scan + dinv fused, 256/block
__global__ void k_scan1(const int* __restrict__ deg, int* __restrict__ off,
                        int* __restrict__ bsum, float* __restrict__ dinv, int n) {
    __shared__ int s[256];
    int t = threadIdx.x;
    int i = blockIdx.x * 256 + t;
    int v = (i < n) ? deg[i] : 0;
    if (i < n) dinv[i] = rsqrtf((float)(v + 1));   // +1 self-loop
    s[t] = v;
    __syncthreads();
    #pragma unroll
    for (int d = 1; d < 256; d <<= 1) {
        int x = (t >= d) ? s[t - d] : 0;
        __syncthreads();
        s[t] += x;
        __syncthreads();
    }
    if (i < n) off[i] = s[t] - v;            // exclusive within block
    if (t == 255) bsum[blockIdx.x] = s[255];
}

__global__ void k_scan2(int* __restrict__ bsum, int nb) {
    __shared__ int s[512];
    int t = threadIdx.x;
    int v = (t < nb) ? bsum[t] : 0;
    s[t] = v;
    __syncthreads();
    #pragma unroll
    for (int d = 1; d < 512; d <<= 1) {
        int x = (t >= d) ? s[t - d] : 0;
        __syncthreads();
        s[t] += x;
        __syncthreads();
    }
    if (t < nb) bsum[t] = s[t] - v;          // exclusive block offsets
}

__global__ void k_scan3(int* __restrict__ off, const int* __restrict__ bsum,
                        int* __restrict__ cur, int n) {
    int i = blockIdx.x * blockDim.x + threadIdx.x;
    if (i < n) {
        int o = off[i] + bsum[i >> 8];
        off[i] = o;
        cur[i] = o;
    }
    if (i == n) off[n] = N_EDGES;
}

__global__ void k_scatter(const int* __restrict__ esrc, const int* __restrict__ edst,
                          const float* __restrict__ dinv,
                          int* __restrict__ cur, int* __restrict__ csr_src,
                          float* __restrict__ csr_w) {
    int e = blockIdx.x * blockDim.x + threadIdx.x;
    if (e >= N_EDGES) return;
    int s = esrc[e], d = edst[e];
    int pos = atomicAdd(&cur[d], 1);
    csr_src[pos] = s;
    csr_w[pos] = dinv[s] * dinv[d];
}

// ================= bf16 hi/lo split of 5 x (128x128) W into MFMA fragment layout ====
// frag index for (k, c): lane = ((k>>3)&3)*16 + (c&15), elem = k&7, tile = (k>>5)*8 + (c>>4)
struct SplitArgs {
    const float* W[5];
    unsigned short* Wh[5];
    unsigned short* Wl[5];
};
__global__ void k_split_all(SplitArgs a) {
    int which = blockIdx.x >> 6;                    // 64 blocks per matrix
    int idx = (blockIdx.x & 63) * 256 + threadIdx.x;
    if (idx >= 128 * 128) return;
    int k = idx >> 7, c = idx & 127;
    float wv = a.W[which][idx];
    unsigned short h = bf16_of(wv);
    unsigned short lo = bf16_of(wv - f32_of(h));
    int fi = (((k >> 5) * 8 + (c >> 4)) * 64 + (((k >> 3) & 3) * 16 + (c & 15))) * 8 + (k & 7);
    a.Wh[which][fi] = h;
    a.Wl[which][fi] = lo;
}

// ================= MFMA node GEMM: out = (relu?)in[N,128] @ W[128,128] =================
// bf16x3 error-compensated. 512 threads = 8 waves x 16 rows; R row-tiles per block.
// In-place safe (out==in): each wave reads only its own 16 rows (regs) before writing them.
template<bool RELU>
__global__ __launch_bounds__(512) void k_gemm_mfma(
    const float* __restrict__ in,
    const unsigned short* __restrict__ Whf, const unsigned short* __restrict__ Wlf,
    float* __restrict__ outp, int nrows, int rtiles)
{
    __shared__ __align__(16) unsigned short sWh[16384];
    __shared__ __align__(16) unsigned short sWl[16384];
    const int t = threadIdx.x;

    #pragma unroll
    for (int i = 0; i < 4; ++i) {
        ((float4*)sWh)[t + 512 * i] = ((const float4*)Whf)[t + 512 * i];
        ((float4*)sWl)[t + 512 * i] = ((const float4*)Wlf)[t + 512 * i];
    }
    __syncthreads();

    const int w = t >> 6, l = t & 63;
    const int lr = l & 15, lk = l >> 4;

    for (int r = 0; r < rtiles; ++r) {
        const int row0 = (blockIdx.x * rtiles + r) * 128;
        int arow = row0 + w * 16 + lr;
        if (arow >= nrows) arow = nrows - 1;     // clamp (stores are guarded)
        const float* inrow = in + (size_t)arow * 128 + lk * 8;

        bf16x8 ah[4], al[4];
        #pragma unroll
        for (int ks = 0; ks < 4; ++ks) {
            float4 p0 = *(const float4*)(inrow + ks * 32);
            float4 p1 = *(const float4*)(inrow + ks * 32 + 4);
            float z[8] = {p0.x, p0.y, p0.z, p0.w, p1.x, p1.y, p1.z, p1.w};
            #pragma unroll
            for (int e = 0; e < 8; ++e) {
                float zv = RELU ? fmaxf(z[e], 0.f) : z[e];
                unsigned short hu = bf16_of(zv);
                ah[ks][e] = (short)hu;
                al[ks][e] = (short)bf16_of(zv - f32_of(hu));
            }
        }

        f32x4 acc[8];
        #pragma unroll
        for (int ct = 0; ct < 8; ++ct) { f32x4 zz = {0.f, 0.f, 0.f, 0.f}; acc[ct] = zz; }

        #pragma unroll
        for (int ct = 0; ct < 8; ++ct) {
            #pragma unroll
            for (int ks = 0; ks < 4; ++ks) {
                const bf16x8 bh = *(const bf16x8*)(sWh + ((ks * 8 + ct) * 64 + l) * 8);
                const bf16x8 bl = *(const bf16x8*)(sWl + ((ks * 8 + ct) * 64 + l) * 8);
                acc[ct] = __builtin_amdgcn_mfma_f32_16x16x32_bf16(ah[ks], bh, acc[ct], 0, 0, 0);
                acc[ct] = __builtin_amdgcn_mfma_f32_16x16x32_bf16(ah[ks], bl, acc[ct], 0, 0, 0);
                acc[ct] = __builtin_amdgcn_mfma_f32_16x16x32_bf16(al[ks], bh, acc[ct], 0, 0, 0);
            }
        }

        // D: row m = lk*4 + j (within wave tile), col = ct*16 + lr
        #pragma unroll
        for (int j = 0; j < 4; ++j) {
            int m = row0 + w * 16 + lk * 4 + j;
            if (m < nrows) {
                #pragma unroll
                for (int ct = 0; ct < 8; ++ct)
                    outp[(size_t)m * 128 + ct * 16 + lr] = acc[ct][j];
            }
        }
    }
}

// ================= MFMA P/Q GEMM: P = relu(in)@Wm1_top, Q = relu(in)@Wm1_bot ==========
// Two passes sharing one LDS region; in-place safe for Q==in (input re-read each pass).
__global__ __launch_bounds__(512) void k_gemm_pq_mfma(
    const float* __restrict__ in,
    const unsigned short* __restrict__ Wh0, const unsigned short* __restrict__ Wl0,
    const unsigned short* __restrict__ Wh1, const unsigned short* __restrict__ Wl1,
    float* __restrict__ P, float* __restrict__ Q, int nrows, int rtiles)
{
    __shared__ __align__(16) unsigned short sWh[16384];
    __shared__ __align__(16) unsigned short sWl[16384];
    const int t = threadIdx.x;
    const int w = t >> 6, l = t & 63;
    const int lr = l & 15, lk = l >> 4;

    #pragma unroll
    for (int half = 0; half < 2; ++half) {
        const unsigned short* Whf = half ? Wh1 : Wh0;
        const unsigned short* Wlf = half ? Wl1 : Wl0;
        float* outp = half ? Q : P;
        if (half) __syncthreads();     // all waves done reading previous sW
        #pragma unroll
        for (int i = 0; i < 4; ++i) {
            ((float4*)sWh)[t + 512 * i] = ((const float4*)Whf)[t + 512 * i];
            ((float4*)sWl)[t + 512 * i] = ((const float4*)Wlf)[t + 512 * i];
        }
        __syncthreads();

        for (int r = 0; r < rtiles; ++r) {
            const int row0 = (blockIdx.x * rtiles + r) * 128;
            int arow = row0 + w * 16 + lr;
            if (arow >= nrows) arow = nrows - 1;
            const float* inrow = in + (size_t)arow * 128 + lk * 8;

            bf16x8 ah[4], al[4];
            #pragma unroll
            for (int ks = 0; ks < 4; ++ks) {
                float4 p0 = *(const float4*)(inrow + ks * 32);
                float4 p1 = *(const float4*)(inrow + ks * 32 + 4);
                float z[8] = {p0.x, p0.y, p0.z, p0.w, p1.x, p1.y, p1.z, p1.w};
                #pragma unroll
                for (int e = 0; e < 8; ++e) {
                    float zv = fmaxf(z[e], 0.f);
                    unsigned short hu = bf16_of(zv);
                    ah[ks][e] = (short)hu;
                    al[ks][e] = (short)bf16_of(zv - f32_of(hu));
                }
            }

            f32x4 acc[8];
            #pragma unroll
            for (int ct = 0; ct < 8; ++ct) { f32x4 zz = {0.f, 0.f, 0.f, 0.f}; acc[ct] = zz; }

            #pragma unroll
            for (int ct = 0; ct < 8; ++ct) {
                #pragma unroll
                for (int ks = 0; ks < 4; ++ks) {
                    const bf16x8 bh = *(const bf16x8*)(sWh + ((ks * 8 + ct) * 64 + l) * 8);
                    const bf16x8 bl = *(const bf16x8*)(sWl + ((ks * 8 + ct) * 64 + l) * 8);
                    acc[ct] = __builtin_amdgcn_mfma_f32_16x16x32_bf16(ah[ks], bh, acc[ct], 0, 0, 0);
                    acc[ct] = __builtin_amdgcn_mfma_f32_16x16x32_bf16(ah[ks], bl, acc[ct], 0, 0, 0);
                    acc[ct] = __builtin_amdgcn_mfma_f32_16x16x32_bf16(al[ks], bh, acc[ct], 0, 0, 0);
                }
            }

            #pragma unroll
            for (int j = 0; j < 4; ++j) {
                int m = row0 + w * 16 + lk * 4 + j;
                if (m < nrows) {
                    #pragma unroll
                    for (int ct = 0; ct < 8; ++ct)
                        outp[(size_t)m * 128 + ct * 16 + lr] = acc[ct][j];
                }
            }
        }
    }
}

// ================= CSR aggregation =================
// out[i][:] = bias[:] + dinv[i]^2 * raw[i][:] + sum_{e: dst=i} w_e * raw[src_e][:]
// 8 nodes/block, 32 lanes/node. Neighbor (src,w) prefetched lane-parallel, then
// shfl-broadcast -> row gathers are independent (no serial idx->row load chain).
__global__ __launch_bounds__(256) void k_agg_csr(
    const float* __restrict__ raw, const float* __restrict__ dinv,
    const int* __restrict__ off, const int* __restrict__ csr_src,
    const float* __restrict__ csr_w, const float* __restrict__ bias,
    float* __restrict__ outp)
{
    const int t = threadIdx.x;
    const int node = blockIdx.x * 8 + (t >> 5);
    const int lane = t & 31;
    if (node >= N_NODES) return;

    float di = dinv[node];
    float w0 = di * di;
    float4 acc = ((const float4*)bias)[lane];
    float4 v = ((const float4*)raw)[(size_t)node * 32 + lane];
    acc.x += w0 * v.x; acc.y += w0 * v.y; acc.z += w0 * v.z; acc.w += w0 * v.w;

    const int beg = off[node], end = off[node + 1];
    for (int base = beg; base < end; base += 32) {
        int cnt = end - base;
        if (cnt > 32) cnt = 32;
        int sj = 0;
        float wj = 0.f;
        if (lane < cnt) {
            sj = csr_src[base + lane];
            wj = csr_w[base + lane];
        }
        for (int j = 0; j < cnt; ++j) {
            int s = __shfl(sj, j, 32);
            float w = __shfl(wj, j, 32);
            float4 u = ((const float4*)raw)[(size_t)s * 32 + lane];
            acc.x += w * u.x; acc.y += w * u.y; acc.z += w * u.z; acc.w += w * u.w;
        }
    }
    ((float4*)outp)[(size_t)node * 32 + lane] = acc;
}

// ================= fused edge MLP (MFMA bf16x3, 8 waves / 128 edges per block) =========
// Identical per-thread code to the proven round-5 kernel; only block shape changed
// (512 threads, 128 edges) for 2x occupancy. No runtime work loop (round-6 lesson).
__global__ __launch_bounds__(512) void k_edge_mlp_mfma(
    const int* __restrict__ esrc, const int* __restrict__ edst,
    const float* __restrict__ P, const float* __restrict__ Q,
    const float* __restrict__ bm1,
    const unsigned short* __restrict__ Whf, const unsigned short* __restrict__ Wlf,
    const float* __restrict__ bm2,
    const float* __restrict__ Wm3, const float* __restrict__ bm3,
    float* __restrict__ outp)
{
    __shared__ __align__(16) unsigned short sWh[16384];   // 32 KB, fragment layout
    __shared__ __align__(16) unsigned short sWl[16384];   // 32 KB
    __shared__ int sIdx[2][128];

    const int t = threadIdx.x;
    const int e0 = blockIdx.x * 128;

    // linear stage of pre-swizzled W fragments (2048 float4 each, 512 threads)
    #pragma unroll
    for (int i = 0; i < 4; ++i) {
        ((float4*)sWh)[t + 512 * i] = ((const float4*)Whf)[t + 512 * i];
        ((float4*)sWl)[t + 512 * i] = ((const float4*)Wlf)[t + 512 * i];
    }
    if (t < 128) sIdx[0][t] = esrc[e0 + t];
    else if (t < 256) sIdx[1][t - 128] = edst[e0 + t - 128];
    __syncthreads();

    const int w = t >> 6;          // wave id 0..7: rows w*16 .. w*16+15
    const int l = t & 63;
    const int lr = l & 15;         // A row within tile / D col
    const int lk = l >> 4;         // k-block
    const int row = w * 16 + lr;
    const int s = sIdx[0][row], d = sIdx[1][row];
    const float* prow = P + (size_t)s * 128 + lk * 8;
    const float* qrow = Q + (size_t)d * 128 + lk * 8;
    const float* brow = bm1 + lk * 8;

    // build A-fragments (z1 hi/lo) in registers
    bf16x8 ah[4], al[4];
    #pragma unroll
    for (int ks = 0; ks < 4; ++ks) {
        float4 p0 = *(const float4*)(prow + ks * 32);
        float4 p1 = *(const float4*)(prow + ks * 32 + 4);
        float4 q0 = *(const float4*)(qrow + ks * 32);
        float4 q1 = *(const float4*)(qrow + ks * 32 + 4);
        float4 b0 = *(const float4*)(brow + ks * 32);
        float4 b1 = *(const float4*)(brow + ks * 32 + 4);
        float z[8];
        z[0] = fmaxf(p0.x + q0.x + b0.x, 0.f);
        z[1] = fmaxf(p0.y + q0.y + b0.y, 0.f);
        z[2] = fmaxf(p0.z + q0.z + b0.z, 0.f);
        z[3] = fmaxf(p0.w + q0.w + b0.w, 0.f);
        z[4] = fmaxf(p1.x + q1.x + b1.x, 0.f);
        z[5] = fmaxf(p1.y + q1.y + b1.y, 0.f);
        z[6] = fmaxf(p1.z + q1.z + b1.z, 0.f);
        z[7] = fmaxf(p1.w + q1.w + b1.w, 0.f);
        #pragma unroll
        for (int e = 0; e < 8; ++e) {
            unsigned short hu = bf16_of(z[e]);
            ah[ks][e] = (short)hu;
            al[ks][e] = (short)bf16_of(z[e] - f32_of(hu));
        }
    }

    // C = z1 @ Wm2 + bm2  (8 col tiles of 16)
    f32x4 acc[8];
    #pragma unroll
    for (int ct = 0; ct < 8; ++ct) {
        float bv = bm2[ct * 16 + lr];
        f32x4 a = {bv, bv, bv, bv};
        acc[ct] = a;
    }

    #pragma unroll
    for (int ct = 0; ct < 8; ++ct) {
        #pragma unroll
        for (int ks = 0; ks < 4; ++ks) {
            const bf16x8 bh = *(const bf16x8*)(sWh + ((ks * 8 + ct) * 64 + l) * 8);
            const bf16x8 bl = *(const bf16x8*)(sWl + ((ks * 8 + ct) * 64 + l) * 8);
            acc[ct] = __builtin_amdgcn_mfma_f32_16x16x32_bf16(ah[ks], bh, acc[ct], 0, 0, 0);
            acc[ct] = __builtin_amdgcn_mfma_f32_16x16x32_bf16(ah[ks], bl, acc[ct], 0, 0, 0);
            acc[ct] = __builtin_amdgcn_mfma_f32_16x16x32_bf16(al[ks], bh, acc[ct], 0, 0, 0);
        }
    }

    // out = sigmoid(relu(C) @ Wm3 + bm3); D layout: col = lr, row = lk*4 + reg
    float w3v[8];
    #pragma unroll
    for (int ct = 0; ct < 8; ++ct) w3v[ct] = Wm3[ct * 16 + lr];
    float b3 = bm3[0];
    #pragma unroll
    for (int j = 0; j < 4; ++j) {
        float pj = 0.f;
        #pragma unroll
        for (int ct = 0; ct < 8; ++ct) pj += fmaxf(acc[ct][j], 0.f) * w3v[ct];
        pj += __shfl_xor(pj, 1);
        pj += __shfl_xor(pj, 2);
        pj += __shfl_xor(pj, 4);
        pj += __shfl_xor(pj, 8);
        if (lr == 0)
            outp[e0 + w * 16 + lk * 4 + j] = 1.f / (1.f + expf(-(pj + b3)));
    }
}

// ================= launch =================
extern "C" void kernel_launch(void* const* d_in, const int* in_sizes, int n_in,
                              void* d_out, int out_size, void* d_ws, size_t ws_size,
                              hipStream_t stream) {
    const float* x   = (const float*)d_in[0];
    const int*   ei  = (const int*)d_in[1];
    const float* W1  = (const float*)d_in[2];
    const float* b1  = (const float*)d_in[3];
    const float* W2  = (const float*)d_in[4];
    const float* b2  = (const float*)d_in[5];
    const float* Wm1 = (const float*)d_in[6];
    const float* bm1 = (const float*)d_in[7];
    const float* Wm2 = (const float*)d_in[8];
    const float* bm2 = (const float*)d_in[9];
    const float* Wm3 = (const float*)d_in[10];
    const float* bm3 = (const float*)d_in[11];
    const int* esrc = ei;
    const int* edst = ei + N_EDGES;
    float* outp = (float*)d_out;

    // workspace layout
    float* ws = (float*)d_ws;
    float* dinv = ws;                                   // 100096 floats
    float* A = ws + 100096;                             // N*128
    float* B = A + (size_t)N_NODES * 128;               // N*128
    int* deg     = (int*)(B + (size_t)N_NODES * 128);   // N
    int* off     = deg + N_NODES;                       // N+1
    int* cur     = off + N_NODES + 1;                   // N
    int* bsum    = cur + N_NODES;                       // 512
    int* csr_src = bsum + 512;                          // E
    float* csr_w = (float*)(csr_src + N_EDGES);         // E
    unsigned short* frag = (unsigned short*)(csr_w + N_EDGES);
    unsigned short* W1h   = frag;                 unsigned short* W1l   = frag + 16384;
    unsigned short* W2h   = frag + 2 * 16384;     unsigned short* W2l   = frag + 3 * 16384;
    unsigned short* Wm1ah = frag + 4 * 16384;     unsigned short* Wm1al = frag + 5 * 16384;
    unsigned short* Wm1bh = frag + 6 * 16384;     unsigned short* Wm1bl = frag + 7 * 16384;
    unsigned short* Wm2h  = frag + 8 * 16384;     unsigned short* Wm2l  = frag + 9 * 16384;

    const int nb = (N_NODES + 255) / 256;               // 391 scan blocks

    // ---- CSR build + W splits ----
    k_zero_deg<<<nb, 256, 0, stream>>>(deg);
    k_hist<<<(N_EDGES + 255) / 256, 256, 0, stream>>>(edst, deg);
    k_scan1<<<nb, 256, 0, stream>>>(deg, off, bsum, dinv, N_NODES);
    k_scan2<<<1, 512, 0, stream>>>(bsum, nb);
    k_scan3<<<(N_NODES + 256) / 256, 256, 0, stream>>>(off, bsum, cur, N_NODES);
    k_scatter<<<(N_EDGES + 255) / 256, 256, 0, stream>>>(esrc, edst, dinv, cur, csr_src, csr_w);

    SplitArgs sa;
    sa.W[0] = W1;  sa.Wh[0] = W1h;   sa.Wl[0] = W1l;
    sa.W[1] = W2;  sa.Wh[1] = W2h;   sa.Wl[1] = W2l;
    sa.W[2] = Wm1; sa.Wh[2] = Wm1ah; sa.Wl[2] = Wm1al;
    sa.W[3] = Wm1 + 128 * 128; sa.Wh[3] = Wm1bh; sa.Wl[3] = Wm1bl;
    sa.W[4] = Wm2; sa.Wh[4] = Wm2h;  sa.Wl[4] = Wm2l;
    k_split_all<<<5 * 64, 256, 0, stream>>>(sa);

    const int RT = 4;                                   // row tiles per block (128 rows each)
    const int gemm_blocks = (N_NODES + 128 * RT - 1) / (128 * RT);   // 196
    const int agg_blocks = (N_NODES + 7) / 8;

    // ---- layer 1: A = x @ W1 ; B = b1 + norm-agg(A) ----
    k_gemm_mfma<false><<<gemm_blocks, 512, 0, stream>>>(x, W1h, W1l, A, N_NODES, RT);
    k_agg_csr<<<agg_blocks, 256, 0, stream>>>(A, dinv, off, csr_src, csr_w, b1, B);

    // ---- layer 2: A = relu(B) @ W2 ; B = b2 + norm-agg(A) ----
    k_gemm_mfma<true><<<gemm_blocks, 512, 0, stream>>>(B, W2h, W2l, A, N_NODES, RT);
    k_agg_csr<<<agg_blocks, 256, 0, stream>>>(A, dinv, off, csr_src, csr_w, b2, B);

    // ---- edge-MLP layer-1 decomposition: P -> A, Q -> B (in-place safe) ----
    k_gemm_pq_mfma<<<gemm_blocks, 512, 0, stream>>>(B, Wm1ah, Wm1al, Wm1bh, Wm1bl,
                                                    A, B, N_NODES, RT);

    // ---- fused edge MLP on MFMA: 6250 blocks x 128 edges, 8 waves ----
    k_edge_mlp_mfma<<<N_EDGES / 128, 512, 0, stream>>>(esrc, edst, A, B, bm1,
                                                       Wm2h, Wm2l, bm2, Wm3, bm3, outp);
}